// Round 1
// 473.924 us; speedup vs baseline: 1.0256x; 1.0256x over previous
//
#include <hip/hip_runtime.h>
#include <math.h>

#define TT 84
#define BB 96
#define GB 6            // batches per group
#define NG 16           // groups (NG*GB == BB)
#define NTOK (TT*BB)
#define RW4 6           // float4s per act row: 24 floats = [fwd 10 | pad 2 | bwd 10 | pad 2]

// Gate-argument pre-scaling folded into weights/biases:
//  r,z rows scaled by -log2(e)   -> sigm(a) = rcp(1 + exp2(arg))
//  n rows scaled by -2*log2(e)   -> tanh(x) = 2*rcp(1 + exp2(arg)) - 1
#define S_RZ (-1.4426950408889634f)
#define S_N  (-2.8853900817779268f)

__device__ __forceinline__ float frcp(float x)  { return __builtin_amdgcn_rcpf(x); }
__device__ __forceinline__ float fexp2(float x) { return __builtin_amdgcn_exp2f(x); }

// ---------------- layer-0 projection: emb gather + E=400 dot (pre-scaled) ----
__global__ __launch_bounds__(256) void proj0_kernel(
    const int* __restrict__ x, const float* __restrict__ emb,
    const float* __restrict__ wih0, const float* __restrict__ bih0,
    float* __restrict__ xp, unsigned int* __restrict__ bar)
{
    if (blockIdx.x == 0 && threadIdx.x == 0) bar[0] = 0u;  // re-zero grid barrier
    __shared__ float4 xrow[32][100];   // 32 tokens x 400 floats
    const int tok0 = blockIdx.x * 32;
    for (int u = threadIdx.x; u < 32*100; u += 256) {
        int tk = u / 100, i4 = u % 100;
        int row = x[tok0 + tk];
        xrow[tk][i4] = ((const float4*)emb)[row*100 + i4];
    }
    __syncthreads();
    const int g64 = threadIdx.x & 63;
    const int q   = threadIdx.x >> 6;          // 0..3, 8 tokens each
    if (g64 >= 60) return;
    const int dir = g64 / 30, gg = g64 % 30;
    const float sc = (gg < 20) ? S_RZ : S_N;
    const float bias = bih0[dir*30 + gg];
    float acc[8];
    #pragma unroll
    for (int c = 0; c < 8; ++c) acc[c] = bias;
    const float4* w4 = ((const float4*)wih0) + (dir*30 + gg)*100;
    for (int i4 = 0; i4 < 100; ++i4) {
        float4 w = w4[i4];
        #pragma unroll
        for (int c = 0; c < 8; ++c) {
            float4 xv = xrow[q*8 + c][i4];
            acc[c] += w.x*xv.x + w.y*xv.y + w.z*xv.z + w.w*xv.w;
        }
    }
    #pragma unroll
    for (int c = 0; c < 8; ++c) {
        int tok = tok0 + q*8 + c;
        int t = tok / BB, b = tok % BB;
        xp[((size_t)((dir*TT + t)*BB + b))*30 + gg] = acc[c]*sc;
    }
}

// ---------------- GRU cell: pre-scaled args, h from exchange float4s ---------
__device__ __forceinline__ float gru_cell(
    float xr, float xz, float xn,
    float4 ha, float4 hb, float4 hc,
    const float* wr, const float* wz, const float* wn,
    float bhr, float bhz, float bhn, float& hown)
{
    float hr0 = fmaf(wr[0], ha.x, bhr), hr1 = wr[1]*ha.y;
    float hz0 = fmaf(wz[0], ha.x, bhz), hz1 = wz[1]*ha.y;
    float hn0 = fmaf(wn[0], ha.x, bhn), hn1 = wn[1]*ha.y;
    hr0 = fmaf(wr[2], ha.z, hr0); hr1 = fmaf(wr[3], ha.w, hr1);
    hz0 = fmaf(wz[2], ha.z, hz0); hz1 = fmaf(wz[3], ha.w, hz1);
    hn0 = fmaf(wn[2], ha.z, hn0); hn1 = fmaf(wn[3], ha.w, hn1);
    hr0 = fmaf(wr[4], hb.x, hr0); hr1 = fmaf(wr[5], hb.y, hr1);
    hz0 = fmaf(wz[4], hb.x, hz0); hz1 = fmaf(wz[5], hb.y, hz1);
    hn0 = fmaf(wn[4], hb.x, hn0); hn1 = fmaf(wn[5], hb.y, hn1);
    hr0 = fmaf(wr[6], hb.z, hr0); hr1 = fmaf(wr[7], hb.w, hr1);
    hz0 = fmaf(wz[6], hb.z, hz0); hz1 = fmaf(wz[7], hb.w, hz1);
    hn0 = fmaf(wn[6], hb.z, hn0); hn1 = fmaf(wn[7], hb.w, hn1);
    hr0 = fmaf(wr[8], hc.x, hr0); hr1 = fmaf(wr[9], hc.y, hr1);
    hz0 = fmaf(wz[8], hc.x, hz0); hz1 = fmaf(wz[9], hc.y, hz1);
    hn0 = fmaf(wn[8], hc.x, hn0); hn1 = fmaf(wn[9], hc.y, hn1);
    float r = frcp(1.f + fexp2(xr + hr0 + hr1));
    float z = frcp(1.f + fexp2(xz + hz0 + hz1));
    float an = fmaf(r, hn0 + hn1, xn);
    float n  = fmaf(2.f, frcp(1.f + fexp2(an)), -1.f);
    float hnew = n + z*(hown - n);
    hown = hnew;
    return hnew;
}

// proj over 20 channels from a padded 24-float act row
__device__ __forceinline__ void proj20(
    const float4* A, const float* wpr, const float* wpz, const float* wpn,
    float bir, float biz, float bin, float& xr, float& xz, float& xn)
{
    float a[24];
    #pragma unroll
    for (int q = 0; q < 6; ++q) {
        a[4*q]=A[q].x; a[4*q+1]=A[q].y; a[4*q+2]=A[q].z; a[4*q+3]=A[q].w;
    }
    xr = bir; xz = biz; xn = bin;
    #pragma unroll
    for (int c = 0; c < 20; ++c) {
        float av = a[c + (c >= 10 ? 2 : 0)];
        xr = fmaf(wpr[c], av, xr); xz = fmaf(wpz[c], av, xz); xn = fmaf(wpn[c], av, xn);
    }
}

// ---------------- lean scan: reads pre-computed xp (global), h via LDS -------
__device__ __forceinline__ void scan_layer(
    const float* __restrict__ xb,       // xp + dir plane, layout [t][BB][30]
    const float* __restrict__ wh, const float* __restrict__ bh3,
    float4* __restrict__ act4, float* __restrict__ actG, bool last,
    int bl, int j, bool act_ln, int b, int dir, int dt, int t0)
{
    float wr[10], wz[10], wn[10];
    {
        const float2* p0 = (const float2*)(wh + j*10);
        const float2* p1 = (const float2*)(wh + (10+j)*10);
        const float2* p2 = (const float2*)(wh + (20+j)*10);
        #pragma unroll
        for (int q = 0; q < 5; ++q) {
            float2 a = p0[q]; wr[2*q]=a.x*S_RZ; wr[2*q+1]=a.y*S_RZ;
            float2 c = p1[q]; wz[2*q]=c.x*S_RZ; wz[2*q+1]=c.y*S_RZ;
            float2 d = p2[q]; wn[2*q]=d.x*S_N;  wn[2*q+1]=d.y*S_N;
        }
    }
    const float bhr = bh3[j]*S_RZ, bhz = bh3[10+j]*S_RZ, bhn = bh3[20+j]*S_N;

    float4 ha = {0,0,0,0}, hb = {0,0,0,0}, hc = {0,0,0,0};
    float hown = 0.f;
    int t = t0;
    // 2-deep scalar prefetch of the (independent) projected inputs
    float xr0 = xb[(size_t)(t0*BB + b)*30 + j];
    float xz0 = xb[(size_t)(t0*BB + b)*30 + 10 + j];
    float xn0 = xb[(size_t)(t0*BB + b)*30 + 20 + j];
    const int t1 = t0 + dt;
    float xr1 = xb[(size_t)(t1*BB + b)*30 + j];
    float xz1 = xb[(size_t)(t1*BB + b)*30 + 10 + j];
    float xn1 = xb[(size_t)(t1*BB + b)*30 + 20 + j];

    #pragma unroll 1
    for (int s = 0; s < TT; ++s) {
        float hnew = gru_cell(xr0, xz0, xn0, ha, hb, hc, wr, wz, wn, bhr, bhz, bhn, hown);
        ((float*)&act4[(t*GB + bl)*RW4])[dir*12 + j] = hnew;     // ds_write (exchange + act)
        const float4* hr = &act4[(t*GB + bl)*RW4 + dir*3];
        ha = hr[0]; hb = hr[1]; hc = hr[2];                      // 3x ds_read_b128
        __builtin_amdgcn_sched_barrier(0);                       // keep h-reads oldest in lgkm queue
        if (last && act_ln) actG[(size_t)(t*BB + b)*20 + dir*10 + j] = hnew;
        int tp = t + 2*dt; tp = tp < 0 ? 0 : (tp > TT-1 ? TT-1 : tp);
        xr0 = xr1; xz0 = xz1; xn0 = xn1;
        const float* px = xb + (size_t)(tp*BB + b)*30;
        xr1 = px[j]; xz1 = px[10 + j]; xn1 = px[20 + j];
        t += dt;
    }
}

// ---------------- mega: all 10 layers + head, 16 blocks x 256 ----------------
__global__ __launch_bounds__(256, 1) void mega_kernel(
    float* __restrict__ xp,             // read-write: layer-l inputs, overwritten per layer
    const float* __restrict__ whh0, const float* __restrict__ bhh0,
    const float* __restrict__ wih,  const float* __restrict__ bih,
    const float* __restrict__ whh,  const float* __restrict__ bhh,
    const float* __restrict__ lin_w, const float* __restrict__ lin_b,
    float* __restrict__ actG, unsigned int* __restrict__ bar,
    float* __restrict__ out)
{
    __shared__ float4 act4[TT*GB*RW4];    // 48384 B, single buffer

    const int tid  = threadIdx.x;
    const int grp  = blockIdx.x;

    // scan mapping (waves 0,1)
    const int dir  = (tid >> 6) & 1;
    const int lane = tid & 63;
    int bl = lane / 10; if (bl > 5) bl = 5;
    int j  = lane - bl*10; if (j > 9) j = 9;
    const bool act_ln = (lane < 60);
    const int b  = grp*GB + bl;
    const int dt = dir ? -1 : 1;
    const int t0 = dir ? TT-1 : 0;

    // boundary-proj mapping (240 of 256 threads: 2 t-halves x 2 dir x 6 b x 10 ch)
    const int half = tid / 120;           // 0,1 (tid>=240 unused, guarded below)
    const int prr  = tid % 120;
    const int dp   = prr / 60;
    const int prr2 = prr % 60;
    const int blp  = prr2 / 10;
    const int jp   = prr2 % 10;

    #pragma unroll 1
    for (int l = 0; l < 10; ++l) {
        if (tid < 128) {
            const float* wh  = (l == 0) ? (whh0 + dir*300)
                                        : (whh + (size_t)((l-1)*2 + dir)*300);
            const float* bh3 = (l == 0) ? (bhh0 + dir*30)
                                        : (bhh + (size_t)((l-1)*2 + dir)*30);
            scan_layer(xp + (size_t)dir*TT*BB*30, wh, bh3, act4, actG, (l == 9),
                       bl, j, act_ln, b, dir, dt, t0);
        }
        __syncthreads();
        if (l < 9) {
            // boundary pass: xp for layer l+1 from act4, all 4 waves
            if (tid < 240) {
                const float* wi = wih + (size_t)(l*2 + dp)*600;
                const float* bi = bih + (size_t)(l*2 + dp)*30;
                float wpr[20], wpz[20], wpn[20];
                {
                    const float4* p0 = (const float4*)(wi + jp*20);
                    const float4* p1 = (const float4*)(wi + (10+jp)*20);
                    const float4* p2 = (const float4*)(wi + (20+jp)*20);
                    #pragma unroll
                    for (int q = 0; q < 5; ++q) {
                        float4 a = p0[q]; wpr[4*q]=a.x*S_RZ; wpr[4*q+1]=a.y*S_RZ; wpr[4*q+2]=a.z*S_RZ; wpr[4*q+3]=a.w*S_RZ;
                        float4 c = p1[q]; wpz[4*q]=c.x*S_RZ; wpz[4*q+1]=c.y*S_RZ; wpz[4*q+2]=c.z*S_RZ; wpz[4*q+3]=c.w*S_RZ;
                        float4 d = p2[q]; wpn[4*q]=d.x*S_N;  wpn[4*q+1]=d.y*S_N;  wpn[4*q+2]=d.z*S_N;  wpn[4*q+3]=d.w*S_N;
                    }
                }
                const float bir = bi[jp]*S_RZ, biz = bi[10+jp]*S_RZ, bin = bi[20+jp]*S_N;
                const int bg = grp*GB + blp;
                #pragma unroll 1
                for (int t = half*(TT/2); t < (half+1)*(TT/2); ++t) {
                    float xr, xz, xn;
                    proj20(&act4[(t*GB + blp)*RW4], wpr, wpz, wpn, bir, biz, bin, xr, xz, xn);
                    float* px = xp + ((size_t)(dp*TT + t)*BB + bg)*30;
                    px[jp] = xr; px[10+jp] = xz; px[20+jp] = xn;
                }
            }
            __syncthreads();
        }
    }

    // ---- grid barrier (16 blocks, all co-resident) ----
    __threadfence();
    __syncthreads();
    if (tid == 0) {
        __hip_atomic_fetch_add(bar, 1u, __ATOMIC_ACQ_REL, __HIP_MEMORY_SCOPE_AGENT);
        while (__hip_atomic_load(bar, __ATOMIC_ACQUIRE, __HIP_MEMORY_SCOPE_AGENT) < (unsigned)NG)
            __builtin_amdgcn_s_sleep(1);
    }
    __syncthreads();
    __threadfence();

    // ---- head: rows r = grp*6 .. grp*6+5 (feat aliases act4) ----
    float* feat = (float*)act4;
    for (int u = tid; u < GB*336; u += 256) {
        int q = u / 336, v = u % 336;
        int r = grp*GB + q;
        int qq = v / 12, f = v % 12;
        int pair = r*28 + qq;           // t*32 + bb
        int t = pair / 32, bb = pair % 32;
        int jj = (f < 6) ? f : f - 6;
        float acc = (f < 6) ? 0.f : -1e30f;
        #pragma unroll
        for (int i = 0; i < 3; ++i) {
            #pragma unroll
            for (int kk = 0; kk < 3; ++kk) {
                float vv = actG[(size_t)(t*BB + bb*3 + i)*20 + jj*3 + kk];
                if (f < 6) acc += vv; else acc = fmaxf(acc, vv);
            }
        }
        feat[u] = (f < 6) ? acc*(1.f/9.f) : acc;
    }
    __syncthreads();
    if (tid < GB*19) {
        int q = tid / 19, o = tid % 19;
        int r = grp*GB + q;
        float acc = lin_b[o];
        const float* wrow = lin_w + o*336;
        const float* frow = feat + q*336;
        for (int v = 0; v < 336; ++v) acc = fmaf(frow[v], wrow[v], acc);
        out[r*19 + o] = frcp(1.f + __expf(-acc));
    }
}

extern "C" void kernel_launch(void* const* d_in, const int* in_sizes, int n_in,
                              void* d_out, int out_size, void* d_ws, size_t ws_size,
                              hipStream_t stream)
{
    const int*   x     = (const int*)  d_in[0];
    const float* emb   = (const float*)d_in[1];
    const float* wih0  = (const float*)d_in[2];
    const float* whh0  = (const float*)d_in[3];
    const float* bih0  = (const float*)d_in[4];
    const float* bhh0  = (const float*)d_in[5];
    const float* wih   = (const float*)d_in[6];
    const float* whh   = (const float*)d_in[7];
    const float* bih   = (const float*)d_in[8];
    const float* bhh   = (const float*)d_in[9];
    const float* lin_w = (const float*)d_in[10];
    const float* lin_b = (const float*)d_in[11];
    float* out = (float*)d_out;

    float* xp0  = (float*)d_ws;                    // 2*84*96*30 = 483840 floats
    float* actG = xp0 + (size_t)2*NTOK*30;         // 84*96*20   = 161280 floats
    unsigned int* bar = (unsigned int*)(actG + (size_t)NTOK*20);

    proj0_kernel<<<252, 256, 0, stream>>>(x, emb, wih0, bih0, xp0, bar);
    mega_kernel<<<NG, 256, 0, stream>>>(xp0, whh0, bhh0, wih, bih, whh, bhh,
                                        lin_w, lin_b, actG, bar, out);
}